// Round 1
// baseline (471.234 us; speedup 1.0000x reference)
//
#include <hip/hip_runtime.h>
#include <hip/hip_bf16.h>
#include <cmath>
#include <stdint.h>

#define B_ 2
#define S_ 2048
#define D_ 2048
#define H_ 16
#define HKV_ 2
#define DH_ 128
#define G_ 8
#define DKV_ 256   // HKV*DH

typedef _Float16 f16;
typedef _Float16 f16x8 __attribute__((ext_vector_type(8)));
typedef _Float16 f16x4 __attribute__((ext_vector_type(4)));
typedef float f32x4 __attribute__((ext_vector_type(4)));

__device__ __forceinline__ void gload_lds16(const void* g, void* lds) {
  __builtin_amdgcn_global_load_lds((const __attribute__((address_space(1))) void*)g,
                                   (__attribute__((address_space(3))) void*)lds,
                                   16, 0, 0);
}

__global__ void cast_kernel(const float* __restrict__ in, f16* __restrict__ out, int n4) {
  int i = blockIdx.x * blockDim.x + threadIdx.x;
  int stride = gridDim.x * blockDim.x;
  for (; i < n4; i += stride) {
    float4 v = reinterpret_cast<const float4*>(in)[i];
    f16x4 o = { (f16)v.x, (f16)v.y, (f16)v.z, (f16)v.w };
    reinterpret_cast<f16x4*>(out)[i] = o;
  }
}

// C[m][n] = sum_k A[m][k] * Bm[n][k] + bias[n]
// A: (M,K) f16 row-major, Bm: (N,K) f16 row-major.  M%128==0, N%128==0, K%64==0.
template<typename OUT_T>
__global__ __launch_bounds__(256)
void gemm_bt(const f16* __restrict__ A, const f16* __restrict__ Bm,
             const float* __restrict__ bias, OUT_T* __restrict__ C,
             int M, int N, int K) {
  __shared__ __align__(16) f16 sA[128 * 64];
  __shared__ __align__(16) f16 sB[128 * 64];
  const int tid  = threadIdx.x;
  const int lane = tid & 63;
  const int w    = tid >> 6;        // wave 0..3
  const int wr   = w >> 1, wc = w & 1;
  const int r16  = lane & 15, grp = lane >> 4;
  const int bm = blockIdx.y * 128;
  const int bn = blockIdx.x * 128;

  f32x4 acc[4][4] = {};

  for (int k0 = 0; k0 < K; k0 += 64) {
    // stage 128x64 A-tile and B-tile: 16 segments x 512 elems; wave w does segs j*4+w
#pragma unroll
    for (int j = 0; j < 4; ++j) {
      int seg = j * 4 + w;
      int e = seg * 512 + lane * 8;
      int r = e >> 6, c = e & 63;
      gload_lds16(A  + (size_t)(bm + r) * K + k0 + c, &sA[seg * 512]);
      gload_lds16(Bm + (size_t)(bn + r) * K + k0 + c, &sB[seg * 512]);
    }
    asm volatile("s_waitcnt vmcnt(0)" ::: "memory");
    __syncthreads();

#pragma unroll
    for (int kk = 0; kk < 64; kk += 32) {
      f16x8 af[4], bf[4];
#pragma unroll
      for (int m = 0; m < 4; ++m)
        af[m] = *reinterpret_cast<const f16x8*>(&sA[(wr * 64 + m * 16 + r16) * 64 + kk + grp * 8]);
#pragma unroll
      for (int n = 0; n < 4; ++n)
        bf[n] = *reinterpret_cast<const f16x8*>(&sB[(wc * 64 + n * 16 + r16) * 64 + kk + grp * 8]);
#pragma unroll
      for (int m = 0; m < 4; ++m)
#pragma unroll
        for (int n = 0; n < 4; ++n)
          acc[m][n] = __builtin_amdgcn_mfma_f32_16x16x32_f16(af[m], bf[n], acc[m][n], 0, 0, 0);
    }
    __syncthreads();
  }

  // epilogue: C layout per 16x16 frag: col = lane&15, row = grp*4 + j
#pragma unroll
  for (int n = 0; n < 4; ++n) {
    int col = bn + wc * 64 + n * 16 + r16;
    float bv = bias ? bias[col] : 0.f;
#pragma unroll
    for (int m = 0; m < 4; ++m) {
      int row0 = bm + wr * 64 + m * 16 + grp * 4;
#pragma unroll
      for (int j = 0; j < 4; ++j) {
        float v = acc[m][n][j] + bv;
        C[(size_t)(row0 + j) * N + col] = (OUT_T)v;
      }
    }
  }
}

// Flash attention, causal, GQA. 1 wave per block, 16 q-rows per block.
// Q: (B*S, D) f16; K,V: (B*S, DKV) f16; O: (B*S, D) f16.
__global__ __launch_bounds__(64)
void attn_kernel(const f16* __restrict__ Q, const f16* __restrict__ K,
                 const f16* __restrict__ V, f16* __restrict__ O) {
  const int lane = threadIdx.x;
  const int qi = lane & 15, grp = lane >> 4;
  const int qt = blockIdx.x;       // 16-row q tile
  const int hq = blockIdx.y;       // query head 0..15
  const int b  = blockIdx.z;
  const int kvh = hq >> 3;         // kv head = hq / G
  const float INV_SCALE = 0.08838834764831845f;  // 1/sqrt(128)

  // Q fragments (B-operand of swapped QK^T): lane holds Q[q=qi][d=kd*32+grp*8 ..+7]
  const size_t qbase = ((size_t)(b * S_ + qt * 16 + qi)) * D_ + hq * DH_;
  f16x8 qf[4];
#pragma unroll
  for (int kd = 0; kd < 4; ++kd)
    qf[kd] = *reinterpret_cast<const f16x8*>(Q + qbase + kd * 32 + grp * 8);

  float m = -INFINITY, lsum = 0.f;
  f32x4 accO[8] = {};  // O^T: accO[dt][j] = O[q=qi][d=dt*16+grp*4+j]

  const int q_pos = qt * 16 + qi;
  const f16* Kh = K + (size_t)b * S_ * DKV_ + kvh * DH_;
  const f16* Vh = V + (size_t)b * S_ * DKV_ + kvh * DH_;

  for (int kv0 = 0; kv0 <= qt * 16; kv0 += 16) {
    // S^T[kv][q] = sum_d K[kv,d] Q[q,d]  via mfma(A=K rows, B=Q^T)
    f32x4 s = {};
#pragma unroll
    for (int kd = 0; kd < 4; ++kd) {
      f16x8 kf = *reinterpret_cast<const f16x8*>(Kh + (size_t)(kv0 + qi) * DKV_ + kd * 32 + grp * 8);
      s = __builtin_amdgcn_mfma_f32_16x16x32_f16(kf, qf[kd], s, 0, 0, 0);
    }
    // lane holds S^T[kv0+grp*4+j][q=qi]
    float p[4], tm = -INFINITY;
#pragma unroll
    for (int j = 0; j < 4; ++j) {
      float sv = s[j] * INV_SCALE;
      int kv_pos = kv0 + grp * 4 + j;
      sv = (kv_pos > q_pos) ? -INFINITY : sv;
      p[j] = sv;
      tm = fmaxf(tm, sv);
    }
    tm = fmaxf(tm, __shfl_xor(tm, 16));
    tm = fmaxf(tm, __shfl_xor(tm, 32));
    float m_new = fmaxf(m, tm);
    float scale = __expf(m - m_new);
    float ps = 0.f;
#pragma unroll
    for (int j = 0; j < 4; ++j) {
      p[j] = __expf(p[j] - m_new);
      ps += p[j];
    }
    ps += __shfl_xor(ps, 16);
    ps += __shfl_xor(ps, 32);
    lsum = lsum * scale + ps;
    m = m_new;

    // PV: O^T[d][q] += V^T[d][kv] * P^T[kv][q], K=16 MFMA.
    // B-operand = p[] exactly as laid out (B[k=grp*4+i][col=qi]).
    f16x4 pf = { (f16)p[0], (f16)p[1], (f16)p[2], (f16)p[3] };
#pragma unroll
    for (int dt = 0; dt < 8; ++dt) {
#pragma unroll
      for (int j = 0; j < 4; ++j) accO[dt][j] *= scale;
      f16x4 vf;
#pragma unroll
      for (int i = 0; i < 4; ++i)
        vf[i] = Vh[(size_t)(kv0 + grp * 4 + i) * DKV_ + dt * 16 + qi];
      accO[dt] = __builtin_amdgcn_mfma_f32_16x16x16f16(vf, pf, accO[dt], 0, 0, 0);
    }
  }

  float inv_l = 1.f / lsum;
#pragma unroll
  for (int dt = 0; dt < 8; ++dt)
#pragma unroll
    for (int j = 0; j < 4; ++j)
      O[((size_t)(b * S_ + qt * 16 + qi)) * D_ + hq * DH_ + dt * 16 + grp * 4 + j] =
          (f16)(accO[dt][j] * inv_l);
}

extern "C" void kernel_launch(void* const* d_in, const int* in_sizes, int n_in,
                              void* d_out, int out_size, void* d_ws, size_t ws_size,
                              hipStream_t stream) {
  const float* x  = (const float*)d_in[0];
  const float* Wq = (const float*)d_in[1];
  const float* bq = (const float*)d_in[2];
  const float* Wk = (const float*)d_in[3];
  const float* bk = (const float*)d_in[4];
  const float* Wv = (const float*)d_in[5];
  const float* bv = (const float*)d_in[6];
  const float* Wo = (const float*)d_in[7];
  const float* bo = (const float*)d_in[8];
  float* out = (float*)d_out;

  char* ws = (char*)d_ws;
  size_t off = 0;
  auto alloc = [&](size_t bytes) {
    char* p = ws + off;
    off += (bytes + 255) & ~(size_t)255;
    return p;
  };
  f16* xh  = (f16*)alloc((size_t)B_ * S_ * D_ * 2);
  f16* wqh = (f16*)alloc((size_t)D_ * D_ * 2);
  f16* wkh = (f16*)alloc((size_t)DKV_ * D_ * 2);
  f16* wvh = (f16*)alloc((size_t)DKV_ * D_ * 2);
  f16* woh = (f16*)alloc((size_t)D_ * D_ * 2);
  f16* qh  = (f16*)alloc((size_t)B_ * S_ * D_ * 2);
  f16* kh  = (f16*)alloc((size_t)B_ * S_ * DKV_ * 2);
  f16* vh  = (f16*)alloc((size_t)B_ * S_ * DKV_ * 2);
  f16* ah  = (f16*)alloc((size_t)B_ * S_ * D_ * 2);

  auto cast = [&](const float* in, f16* o, int n) {
    int n4 = n / 4;
    int grid = (n4 + 255) / 256;
    if (grid > 2048) grid = 2048;
    cast_kernel<<<dim3(grid), dim3(256), 0, stream>>>(in, o, n4);
  };
  cast(x,  xh,  B_ * S_ * D_);
  cast(Wq, wqh, D_ * D_);
  cast(Wk, wkh, DKV_ * D_);
  cast(Wv, wvh, DKV_ * D_);
  cast(Wo, woh, D_ * D_);

  const int M = B_ * S_;
  gemm_bt<f16><<<dim3(D_ / 128, M / 128), 256, 0, stream>>>(xh, wqh, bq, qh, M, D_, D_);
  gemm_bt<f16><<<dim3(DKV_ / 128, M / 128), 256, 0, stream>>>(xh, wkh, bk, kh, M, DKV_, D_);
  gemm_bt<f16><<<dim3(DKV_ / 128, M / 128), 256, 0, stream>>>(xh, wvh, bv, vh, M, DKV_, D_);

  attn_kernel<<<dim3(S_ / 16, H_, B_), 64, 0, stream>>>(qh, kh, vh, ah);

  gemm_bt<float><<<dim3(D_ / 128, M / 128), 256, 0, stream>>>(ah, woh, bo, out, M, D_, D_);
}